// Round 1
// baseline (1190.366 us; speedup 1.0000x reference)
//
#include <hip/hip_runtime.h>
#include <math.h>

#define HNUM 16
#define DH 64
#define NSEQ 1024
#define BATCH 2
#define DMODEL 1024
#define SCALE 0.125f
#define EPS 1e-6f
#define NUM_ITER 4

// ---------------------------------------------------------------------------
// GEMM: C[M,Nc] = A[M,K] @ B[Nc,K]^T   (both row-major; B accessed B[n][k])
// 128x128 tile, BK=16, 256 threads, 8x8 per thread, fp32.
// M,Nc multiples of 128; K multiple of 16 (true for all our shapes).
// ---------------------------------------------------------------------------
__global__ __launch_bounds__(256) void gemm_nt_f32(const float* __restrict__ A,
                                                   const float* __restrict__ B,
                                                   float* __restrict__ C,
                                                   int M, int Nc, int K) {
    __shared__ float As[16][132];   // pad 132 -> 528B rows (16B aligned, bank shift)
    __shared__ float Bs[16][132];
    const int tid = threadIdx.x;
    const int tx = tid & 15, ty = tid >> 4;
    const int m0 = blockIdx.y * 128, n0 = blockIdx.x * 128;

    float acc[8][8];
#pragma unroll
    for (int i = 0; i < 8; ++i)
#pragma unroll
        for (int j = 0; j < 8; ++j) acc[i][j] = 0.f;

    for (int k0 = 0; k0 < K; k0 += 16) {
        // load A,B tiles: 128x16 = 512 float4 each, 2 per thread
#pragma unroll
        for (int L = 0; L < 2; ++L) {
            const int idx = tid + L * 256;      // 0..511
            const int r  = idx >> 2;            // 0..127
            const int c4 = (idx & 3) << 2;      // 0,4,8,12
            const float4 av = *reinterpret_cast<const float4*>(
                &A[(size_t)(m0 + r) * K + k0 + c4]);
            As[c4 + 0][r] = av.x; As[c4 + 1][r] = av.y;
            As[c4 + 2][r] = av.z; As[c4 + 3][r] = av.w;
            const float4 bv = *reinterpret_cast<const float4*>(
                &B[(size_t)(n0 + r) * K + k0 + c4]);
            Bs[c4 + 0][r] = bv.x; Bs[c4 + 1][r] = bv.y;
            Bs[c4 + 2][r] = bv.z; Bs[c4 + 3][r] = bv.w;
        }
        __syncthreads();
#pragma unroll
        for (int kk = 0; kk < 16; ++kk) {
            float a[8], b[8];
#pragma unroll
            for (int i = 0; i < 8; ++i) a[i] = As[kk][ty * 8 + i];
#pragma unroll
            for (int j = 0; j < 8; ++j) b[j] = Bs[kk][tx * 8 + j];
#pragma unroll
            for (int i = 0; i < 8; ++i)
#pragma unroll
                for (int j = 0; j < 8; ++j)
                    acc[i][j] = fmaf(a[i], b[j], acc[i][j]);
        }
        __syncthreads();
    }

#pragma unroll
    for (int i = 0; i < 8; ++i) {
#pragma unroll
        for (int j = 0; j < 8; ++j) {
            C[(size_t)(m0 + ty * 8 + i) * Nc + n0 + tx * 8 + j] = acc[i][j];
        }
    }
}

// ---------------------------------------------------------------------------
// Stieltjes attention, one wave (64 lanes) per query row.
// qkv: [B*N, 3*DMODEL] rows laid out [3][H][DH] (natural GEMM output).
// o:   [B, N, H, DH] = [B,N,DMODEL]
// Lane l owns scores j = l + 64*c (c = 0..15, fully unrolled -> registers),
// and output dim d = l for the PV accumulation.
// ---------------------------------------------------------------------------
__global__ __launch_bounds__(256) void stieltjes_attn(const float* __restrict__ qkv,
                                                      float* __restrict__ o) {
    const int wid  = threadIdx.x >> 6;
    const int lane = threadIdx.x & 63;
    const int row  = blockIdx.x * 4 + wid;      // 0 .. B*H*N-1
    const int i = row & (NSEQ - 1);
    const int h = (row >> 10) & (HNUM - 1);
    const int b = row >> 14;

    const size_t rs = 3 * DMODEL;               // qkv row stride (floats)
    const float* qptr  = qkv + (size_t)(b * NSEQ + i) * rs + h * DH;
    const float* kbase = qkv + (size_t)(b * NSEQ) * rs + DMODEL + h * DH;
    const float* vbase = kbase + DMODEL;

    __shared__ __align__(16) float qs[4][DH];
    qs[wid][lane] = qptr[lane];
    __syncthreads();
    const float4* q4 = reinterpret_cast<const float4*>(qs[wid]);

    // ---- scores s_j = (q . k_j) * SCALE, masked entries = -1e30 ----
    float s[16];
#pragma unroll
    for (int c = 0; c < 16; ++c) {
        const int j = lane + (c << 6);
        float acc = -1e30f;
        if (j <= i) {
            const float4* krow = reinterpret_cast<const float4*>(kbase + (size_t)j * rs);
            float a = 0.f;
#pragma unroll
            for (int d4 = 0; d4 < 16; ++d4) {
                const float4 kv = krow[d4];
                const float4 qv = q4[d4];
                a = fmaf(qv.x, kv.x, a); a = fmaf(qv.y, kv.y, a);
                a = fmaf(qv.z, kv.z, a); a = fmaf(qv.w, kv.w, a);
            }
            acc = a * SCALE;
        }
        s[c] = acc;
    }

    // ---- row max -> lambda init ----
    float m = -1e30f;
#pragma unroll
    for (int c = 0; c < 16; ++c) m = fmaxf(m, s[c]);
#pragma unroll
    for (int off = 32; off; off >>= 1) m = fmaxf(m, __shfl_xor(m, off));
    float lam = m + 1.0f;

    // ---- Newton iterations: solve sum 1/(lam - s_j) = 1 ----
    for (int it = 0; it < NUM_ITER; ++it) {
        float f = 0.f, fp = 0.f;                // fp here = sum d^-2 (positive)
#pragma unroll
        for (int c = 0; c < 16; ++c) {
            const int j = lane + (c << 6);
            if (j <= i) {
                const float d   = fmaxf(lam - s[c], EPS);
                const float inv = __builtin_amdgcn_rcpf(d);
                f  += inv;
                fp  = fmaf(inv, inv, fp);
            }
        }
#pragma unroll
        for (int off = 32; off; off >>= 1) {
            f  += __shfl_xor(f, off);
            fp += __shfl_xor(fp, off);
        }
        // ref: lam -= (f-1)/(-fp_pos)  ->  lam += (f-1)/fp_pos
        lam += (f - 1.0f) / fp;
    }

    // ---- final weights + exact normalization ----
    float w[16];
    float sw = 0.f;
#pragma unroll
    for (int c = 0; c < 16; ++c) {
        const int j = lane + (c << 6);
        float ww = 0.f;
        if (j <= i) {
            const float d = fmaxf(lam - s[c], EPS);
            ww = __builtin_amdgcn_rcpf(d);
        }
        w[c] = ww;
        sw += ww;
    }
#pragma unroll
    for (int off = 32; off; off >>= 1) sw += __shfl_xor(sw, off);
    const float invsw = __builtin_amdgcn_rcpf(sw);

    // ---- PV: lane owns output dim d=lane; broadcast weights with shfl ----
    float acc = 0.f;
#pragma unroll
    for (int c = 0; c < 16; ++c) {
        const int j0 = c << 6;
        if (j0 <= i) {                           // uniform across wave
            const int jhi = min(63, i - j0);
            const float* vrow = vbase + (size_t)j0 * rs;
            for (int sl = 0; sl <= jhi; ++sl) {
                const float pj = __shfl(w[c], sl);
                acc = fmaf(pj, vrow[(size_t)sl * rs + lane], acc);
            }
        }
    }
    acc *= invsw;

    o[((size_t)(b * NSEQ + i) * HNUM + h) * DH + lane] = acc;
}

extern "C" void kernel_launch(void* const* d_in, const int* in_sizes, int n_in,
                              void* d_out, int out_size, void* d_ws, size_t ws_size,
                              hipStream_t stream) {
    const float* x    = (const float*)d_in[0];   // [B,N,D]
    const float* Wqkv = (const float*)d_in[1];   // [3D, D]
    const float* Wo   = (const float*)d_in[2];   // [D, D]
    float* out = (float*)d_out;                  // [B,N,D]

    float* qkv = (float*)d_ws;                           // [2048, 3072]
    float* o   = qkv + (size_t)(BATCH * NSEQ) * 3 * DMODEL; // [2048, 1024]

    const int M = BATCH * NSEQ;                  // 2048

    dim3 blk(256);
    dim3 g1(3 * DMODEL / 128, M / 128);
    gemm_nt_f32<<<g1, blk, 0, stream>>>(x, Wqkv, qkv, M, 3 * DMODEL, DMODEL);

    dim3 ga(BATCH * HNUM * NSEQ / 4);
    stieltjes_attn<<<ga, blk, 0, stream>>>(qkv, o);

    dim3 g2(DMODEL / 128, M / 128);
    gemm_nt_f32<<<g2, blk, 0, stream>>>(o, Wo, out, M, DMODEL, DMODEL);
}